// Round 5
// baseline (2007.971 us; speedup 1.0000x reference)
//
#include <hip/hip_runtime.h>

#define NB    8
#define NPTS  16384
#define NS    512
#define NK    64
#define C1    64
#define C2    128
#define RAD2  0.25f
#define MTOT  (NB*NS*NK)   // 262144 rows
// stats layout (floats) in ws after feat:
// [0:64) s0sum | [64:128) s0sq | [128:256) s1sum | [256:384) s1sq
// [384:448) bn0a | [448:512) bn0c | [512:640) bn1a | [640:768) bn1c

// ---------------- FPS: bit-exact farthest point sampling ----------------
// 1024 threads x 16 points. py/pz live in 128 KB dynamic LDS (written once),
// px + running distance dd live in registers (~32 VGPRs of arrays -> no
// allocator pressure fight). One barrier per iteration, double-buffered
// candidate slots. All distance math bit-exact vs reference.
__global__ __launch_bounds__(1024, 4) void fps_kernel(const float* __restrict__ xyz,
                                                      float* __restrict__ out) {
    int b = blockIdx.x;
    int tid = threadIdx.x;
    int lane = tid & 63;
    int w = tid >> 6;  // 16 waves
    const float* base = xyz + (size_t)b * NPTS * 3;
    extern __shared__ float lds[];      // [0:16384) = py, [16384:32768) = pz
    float* py_s = lds;
    float* pz_s = lds + NPTS;
    __shared__ float2 sred[2][16];      // (value, index-bits) per wave, dbuf
    float px[16], dd[16];
#pragma unroll
    for (int j = 0; j < 16; ++j) {
        int p = tid + (j << 10);
        px[j] = base[p * 3 + 0];
        py_s[p] = base[p * 3 + 1];
        pz_s[p] = base[p * 3 + 2];
        dd[j] = 1e10f;
    }
    // iteration 0: centroid is point 0 (uniform broadcast load)
    float cx = base[0], cy = base[1], cz = base[2];
    if (tid == 0) {
        float* o = out + (size_t)b * NS * 3;
        o[0] = cx; o[1] = cy; o[2] = cz;
    }
    __syncthreads();
    for (int i = 1; i < NS; ++i) {
        // 4 independent select chains to break the cmp->cndmask dependency
        float bvA[4] = {-1.f, -1.f, -1.f, -1.f};
        int biA[4] = {0, 0, 0, 0};
#pragma unroll
        for (int j = 0; j < 16; ++j) {
            int p = tid + (j << 10);
            // bit-exact: rn ops, no contraction, sum order ((x+y)+z)
            float dx = __fsub_rn(px[j], cx);
            float dy = __fsub_rn(py_s[p], cy);
            float dz = __fsub_rn(pz_s[p], cz);
            float d = __fadd_rn(__fadd_rn(__fmul_rn(dx, dx), __fmul_rn(dy, dy)),
                                __fmul_rn(dz, dz));
            float nd = fminf(dd[j], d);
            dd[j] = nd;
            int c = j & 3;
            if (nd > bvA[c]) { bvA[c] = nd; biA[c] = p; }  // strict >: lowest j (lowest p) wins in-chain
        }
        float bv = bvA[0];
        int bi = biA[0];
#pragma unroll
        for (int c = 1; c < 4; ++c)
            if (bvA[c] > bv || (bvA[c] == bv && biA[c] < bi)) { bv = bvA[c]; bi = biA[c]; }
        // wave (64) argmax reduce, tie-break min index
#pragma unroll
        for (int off = 32; off >= 1; off >>= 1) {
            float ov = __shfl_xor(bv, off);
            int oi = __shfl_xor(bi, off);
            if (ov > bv || (ov == bv && oi < bi)) { bv = ov; bi = oi; }
        }
        if (lane == 0) sred[i & 1][w] = make_float2(bv, __int_as_float(bi));
        __syncthreads();
        // every thread reduces the 16 wave candidates (broadcast LDS reads,
        // identical order/result in all threads -> uniform winner)
        float v = -1e30f;
        int ii = 0x7fffffff;
#pragma unroll
        for (int k = 0; k < 16; ++k) {
            float2 p2 = sred[i & 1][k];
            float ov = p2.x;
            int oi = __float_as_int(p2.y);
            if (ov > v || (ov == v && oi < ii)) { v = ov; ii = oi; }
        }
        ii = __builtin_amdgcn_readfirstlane(ii);  // uniform -> scalar load path
        const float* cp = base + (size_t)ii * 3;
        cx = cp[0]; cy = cp[1]; cz = cp[2];
        if (tid == 0) {
            float* o = out + ((size_t)b * NS + i) * 3;
            o[0] = cx; o[1] = cy; o[2] = cz;
        }
    }
}

// ------------- Ball query (exact expanded-form distance) + gather -------------
__global__ __launch_bounds__(256) void ballq_kernel(const float* __restrict__ xyz,
                                                    const float* __restrict__ pts,
                                                    const float* __restrict__ newxyz,
                                                    float* __restrict__ feat) {
    int w = threadIdx.x >> 6;
    int lane = threadIdx.x & 63;
    int wid = blockIdx.x * 4 + w;   // 0..4095 == b*512+s
    int b = wid >> 9;
    const float* nx = newxyz + (size_t)wid * 3;
    float cx = nx[0], cy = nx[1], cz = nx[2];
    float sa = __fadd_rn(__fadd_rn(__fmul_rn(cx, cx), __fmul_rn(cy, cy)),
                         __fmul_rn(cz, cz));
    __shared__ int sidx[4][64];
    const float* base = xyz + (size_t)b * NPTS * 3;
    int cnt = 0;
    for (int off = 0; off < NPTS && cnt < NK; off += 64) {
        int p = off + lane;
        float bx = base[p * 3 + 0], by = base[p * 3 + 1], bz = base[p * 3 + 2];
        float sb = __fadd_rn(__fadd_rn(__fmul_rn(bx, bx), __fmul_rn(by, by)),
                             __fmul_rn(bz, bz));
        float dt = __fadd_rn(__fadd_rn(__fmul_rn(cx, bx), __fmul_rn(cy, by)),
                             __fmul_rn(cz, bz));
        float sq = __fsub_rn(__fadd_rn(sa, sb), __fmul_rn(2.0f, dt));
        bool inb = !(sq > RAD2);           // strict >, matches reference
        unsigned long long mask = __ballot(inb);
        int pos = cnt + (int)__popcll(mask & ((1ull << lane) - 1ull));
        if (inb && pos < NK) sidx[w][pos] = p;
        cnt += (int)__popcll(mask);
    }
    __syncthreads();
    int filled = cnt < NK ? cnt : NK;
    int sel = (lane < filled) ? lane : 0;
    int p = (filled > 0) ? sidx[w][sel] : 0;  // filled>0 always (self in radius)
    float gx = base[p * 3 + 0], gy = base[p * 3 + 1], gz = base[p * 3 + 2];
    const float* pb = pts + (size_t)b * NPTS * 3;
    float q0 = pb[p * 3 + 0], q1 = pb[p * 3 + 1], q2 = pb[p * 3 + 2];
    float* fr = feat + ((size_t)wid * NK + lane) * 6;
    fr[0] = __fsub_rn(gx, cx);
    fr[1] = __fsub_rn(gy, cy);
    fr[2] = __fsub_rn(gz, cz);
    fr[3] = q0; fr[4] = q1; fr[5] = q2;
}

// ---------------- Layer-0 stats: per-channel sum/sumsq of h0raw ----------------
__global__ __launch_bounds__(256) void stats0_kernel(const float* __restrict__ feat,
                                                     const float* __restrict__ W0,
                                                     const float* __restrict__ b0,
                                                     float* __restrict__ stats) {
    int lane = threadIdx.x & 63;
    int wid = blockIdx.x * 4 + (threadIdx.x >> 6);  // 0..1023
    float w0[6];
#pragma unroll
    for (int j = 0; j < 6; ++j) w0[j] = W0[lane * 6 + j];
    float bb = b0[lane];
    float ssum = 0.f, ssq = 0.f;
    int r0 = wid * 256;
    for (int r = r0; r < r0 + 256; ++r) {
        const float* f = feat + (size_t)r * 6;
        float h = bb;
#pragma unroll
        for (int j = 0; j < 6; ++j) h = fmaf(w0[j], f[j], h);
        ssum += h;
        ssq = fmaf(h, h, ssq);
    }
    atomicAdd(&stats[lane], ssum);
    atomicAdd(&stats[64 + lane], ssq);
}

__global__ void fin0_kernel(const float* __restrict__ g0, const float* __restrict__ be0,
                            float* __restrict__ stats) {
    int c = threadIdx.x;  // 64 threads
    const float inv = 1.0f / (float)MTOT;  // 2^-18, exact
    float mu = stats[c] * inv;
    float var = fmaxf(stats[64 + c] * inv - mu * mu, 0.f);
    float a = g0[c] * rsqrtf(var + 1e-5f);
    stats[384 + c] = a;
    stats[448 + c] = fmaf(-mu, a, be0[c]);
}

// ---------------- Layer-1 stats: recompute h0n -> h1raw, sum/sumsq ----------------
__global__ __launch_bounds__(256) void stats1_kernel(const float* __restrict__ feat,
                                                     const float* __restrict__ W0,
                                                     const float* __restrict__ b0,
                                                     const float* __restrict__ W1,
                                                     const float* __restrict__ b1,
                                                     float* __restrict__ stats) {
    int lane = threadIdx.x & 63;
    int w = threadIdx.x >> 6;
    int half = w & 1;
    int pairG = blockIdx.x * 2 + (w >> 1);  // 0..2047
    int ch = half * 64 + lane;
    float w0r[6];
#pragma unroll
    for (int j = 0; j < 6; ++j) w0r[j] = W0[lane * 6 + j];
    float b0v = b0[lane];
    float a0 = stats[384 + lane], c0 = stats[448 + lane];
    float w1r[64];
#pragma unroll
    for (int j = 0; j < 64; ++j) w1r[j] = W1[ch * 64 + j];
    float b1v = b1[ch];
    float ssum = 0.f, ssq = 0.f;
    int r0 = pairG * 128;
    for (int r = r0; r < r0 + 128; ++r) {
        const float* f = feat + (size_t)r * 6;
        float h = b0v;
#pragma unroll
        for (int j = 0; j < 6; ++j) h = fmaf(w0r[j], f[j], h);
        float h0n = fmaxf(fmaf(a0, h, c0), 0.f);
        int hbits = __float_as_int(h0n);
        float a0c = 0.f, a1c = 0.f, a2c = 0.f, a3c = 0.f;
#pragma unroll
        for (int j = 0; j < 64; j += 4) {
            a0c = fmaf(w1r[j + 0], __int_as_float(__builtin_amdgcn_readlane(hbits, j + 0)), a0c);
            a1c = fmaf(w1r[j + 1], __int_as_float(__builtin_amdgcn_readlane(hbits, j + 1)), a1c);
            a2c = fmaf(w1r[j + 2], __int_as_float(__builtin_amdgcn_readlane(hbits, j + 2)), a2c);
            a3c = fmaf(w1r[j + 3], __int_as_float(__builtin_amdgcn_readlane(hbits, j + 3)), a3c);
        }
        float acc = b1v + ((a0c + a1c) + (a2c + a3c));
        ssum += acc;
        ssq = fmaf(acc, acc, ssq);
    }
    atomicAdd(&stats[128 + ch], ssum);
    atomicAdd(&stats[256 + ch], ssq);
}

__global__ void fin1_kernel(const float* __restrict__ g1, const float* __restrict__ be1,
                            float* __restrict__ stats) {
    int c = threadIdx.x;  // 128 threads
    const float inv = 1.0f / (float)MTOT;
    float mu = stats[128 + c] * inv;
    float var = fmaxf(stats[256 + c] * inv - mu * mu, 0.f);
    float a = g1[c] * rsqrtf(var + 1e-5f);
    stats[512 + c] = a;
    stats[640 + c] = fmaf(-mu, a, be1[c]);
}

// ---------------- Final: recompute h1n, max over K, write output ----------------
__global__ __launch_bounds__(256) void final_kernel(const float* __restrict__ feat,
                                                    const float* __restrict__ W0,
                                                    const float* __restrict__ b0,
                                                    const float* __restrict__ W1,
                                                    const float* __restrict__ b1,
                                                    const float* __restrict__ stats,
                                                    float* __restrict__ out) {
    int lane = threadIdx.x & 63;
    int w = threadIdx.x >> 6;
    int half = w & 1;
    int g = blockIdx.x * 2 + (w >> 1);  // 0..4095 == b*512+s
    int ch = half * 64 + lane;
    float w0r[6];
#pragma unroll
    for (int j = 0; j < 6; ++j) w0r[j] = W0[lane * 6 + j];
    float b0v = b0[lane];
    float a0 = stats[384 + lane], c0 = stats[448 + lane];
    float w1r[64];
#pragma unroll
    for (int j = 0; j < 64; ++j) w1r[j] = W1[ch * 64 + j];
    float b1v = b1[ch];
    float a1 = stats[512 + ch], c1 = stats[640 + ch];
    float mx = -1e30f;
    int r0 = g * 64;
    for (int k = 0; k < 64; ++k) {
        const float* f = feat + (size_t)(r0 + k) * 6;
        float h = b0v;
#pragma unroll
        for (int j = 0; j < 6; ++j) h = fmaf(w0r[j], f[j], h);
        float h0n = fmaxf(fmaf(a0, h, c0), 0.f);
        int hbits = __float_as_int(h0n);
        float a0c = 0.f, a1c = 0.f, a2c = 0.f, a3c = 0.f;
#pragma unroll
        for (int j = 0; j < 64; j += 4) {
            a0c = fmaf(w1r[j + 0], __int_as_float(__builtin_amdgcn_readlane(hbits, j + 0)), a0c);
            a1c = fmaf(w1r[j + 1], __int_as_float(__builtin_amdgcn_readlane(hbits, j + 1)), a1c);
            a2c = fmaf(w1r[j + 2], __int_as_float(__builtin_amdgcn_readlane(hbits, j + 2)), a2c);
            a3c = fmaf(w1r[j + 3], __int_as_float(__builtin_amdgcn_readlane(hbits, j + 3)), a3c);
        }
        float acc = b1v + ((a0c + a1c) + (a2c + a3c));
        float h1n = fmaxf(fmaf(a1, acc, c1), 0.f);
        mx = fmaxf(mx, h1n);
    }
    out[12288 + (size_t)g * 128 + ch] = mx;
}

extern "C" void kernel_launch(void* const* d_in, const int* in_sizes, int n_in,
                              void* d_out, int out_size, void* d_ws, size_t ws_size,
                              hipStream_t stream) {
    const float* xyz = (const float*)d_in[0];
    const float* pts = (const float*)d_in[1];
    const float* W0  = (const float*)d_in[2];
    const float* b0  = (const float*)d_in[3];
    const float* g0  = (const float*)d_in[4];
    const float* be0 = (const float*)d_in[5];
    const float* W1  = (const float*)d_in[6];
    const float* b1  = (const float*)d_in[7];
    const float* g1  = (const float*)d_in[8];
    const float* be1 = (const float*)d_in[9];
    float* out = (float*)d_out;

    float* feat  = (float*)d_ws;                     // 262144*6 floats = 6.29 MB
    float* stats = feat + (size_t)MTOT * 6;          // 768 floats

    // opt-in to 128 KB dynamic LDS for fps (idempotent, host-side, capture-safe)
    const int fps_lds = 2 * NPTS * (int)sizeof(float);  // 131072
    hipFuncSetAttribute(reinterpret_cast<const void*>(fps_kernel),
                        hipFuncAttributeMaxDynamicSharedMemorySize, fps_lds);

    hipMemsetAsync(stats, 0, 384 * sizeof(float), stream);
    fps_kernel<<<NB, 1024, fps_lds, stream>>>(xyz, out);
    ballq_kernel<<<1024, 256, 0, stream>>>(xyz, pts, out, feat);
    stats0_kernel<<<256, 256, 0, stream>>>(feat, W0, b0, stats);
    fin0_kernel<<<1, 64, 0, stream>>>(g0, be0, stats);
    stats1_kernel<<<1024, 256, 0, stream>>>(feat, W0, b0, W1, b1, stats);
    fin1_kernel<<<1, 128, 0, stream>>>(g1, be1, stats);
    final_kernel<<<2048, 256, 0, stream>>>(feat, W0, b0, W1, b1, stats, out);
}

// Round 6
// 1454.030 us; speedup vs baseline: 1.3810x; 1.3810x over previous
//
#include <hip/hip_runtime.h>

#define NB    8
#define NPTS  16384
#define NS    512
#define NK    64
#define C1    64
#define C2    128
#define RAD2  0.25f
#define MTOT  (NB*NS*NK)   // 262144 rows
// stats layout (floats) in ws after feat:
// [0:64) s0sum | [64:128) s0sq | [128:256) s1sum | [256:384) s1sq
// [384:448) bn0a | [448:512) bn0c | [512:640) bn1a | [640:768) bn1c

// argmax merge step via DPP move (VALU pipe, no LDS traffic).
// Masked-out rows get old==current -> self-compare no-op.
#define ARGMAX_DPP(vb, ib, CTRL, RM)                                          \
    do {                                                                      \
        int _mv = __builtin_amdgcn_update_dpp(vb, vb, CTRL, RM, 0xf, false);  \
        int _mi = __builtin_amdgcn_update_dpp(ib, ib, CTRL, RM, 0xf, false);  \
        float _mf = __int_as_float(_mv);                                      \
        float _bf = __int_as_float(vb);                                       \
        bool _t = (_mf > _bf) || (_mf == _bf && _mi < ib);                    \
        vb = _t ? _mv : vb;                                                   \
        ib = _t ? _mi : ib;                                                   \
    } while (0)

// ---------------- FPS: bit-exact farthest point sampling ----------------
// 1024 threads x 16 points. (py,pz) packed float2 in 128 KB dynamic LDS
// (1 ds_read_b64/point); px + dd in registers. Wave argmax via DPP
// butterfly (no DS ops); block reduce via lane-parallel sred read + 4 DPP
// steps. ONE barrier per iteration. Distance math bit-exact vs reference.
__global__ __launch_bounds__(1024) void fps_kernel(const float* __restrict__ xyz,
                                                   float* __restrict__ out) {
    int b = blockIdx.x;
    int tid = threadIdx.x;
    int lane = tid & 63;
    int w = tid >> 6;  // 16 waves
    const float* base = xyz + (size_t)b * NPTS * 3;
    extern __shared__ float lds[];
    float2* pypz = (float2*)lds;        // [16384] float2 = 128 KB
    __shared__ float2 sred[2][16];      // per-wave (value, index-bits), dbuf
    float px[16], dd[16];
#pragma unroll
    for (int j = 0; j < 16; ++j) {
        int p = tid + (j << 10);
        px[j] = base[p * 3 + 0];
        pypz[p] = make_float2(base[p * 3 + 1], base[p * 3 + 2]);
        dd[j] = 1e10f;
    }
    // iteration 0: centroid is point 0
    float cx = base[0], cy = base[1], cz = base[2];
    if (tid == 0) {
        float* o = out + (size_t)b * NS * 3;
        o[0] = cx; o[1] = cy; o[2] = cz;
    }
    __syncthreads();
    for (int i = 1; i < NS; ++i) {
        // 4 independent select chains (value + small j index)
        float bvA[4] = {-1.f, -1.f, -1.f, -1.f};
        int bjA[4] = {0, 0, 0, 0};
#pragma unroll
        for (int j = 0; j < 16; ++j) {
            int p = tid + (j << 10);
            float2 yz = pypz[p];
            // bit-exact: rn ops, no contraction, sum order ((x+y)+z)
            float dx = __fsub_rn(px[j], cx);
            float dy = __fsub_rn(yz.x, cy);
            float dz = __fsub_rn(yz.y, cz);
            float d = __fadd_rn(__fadd_rn(__fmul_rn(dx, dx), __fmul_rn(dy, dy)),
                                __fmul_rn(dz, dz));
            float nd = fminf(dd[j], d);
            dd[j] = nd;
            int c = j & 3;
            if (nd > bvA[c]) { bvA[c] = nd; bjA[c] = j; }  // strict >: lowest j wins in-chain
        }
        float bv = bvA[0];
        int bj = bjA[0];
#pragma unroll
        for (int c = 1; c < 4; ++c)
            if (bvA[c] > bv || (bvA[c] == bv && bjA[c] < bj)) { bv = bvA[c]; bj = bjA[c]; }
        int vb = __float_as_int(bv);
        int ib = tid + (bj << 10);  // full point index
        // wave(64) argmax, tie-break min index — all DPP, winner in lane 63
        ARGMAX_DPP(vb, ib, 0xB1, 0xf);   // quad_perm xor1
        ARGMAX_DPP(vb, ib, 0x4E, 0xf);   // quad_perm xor2
        ARGMAX_DPP(vb, ib, 0x141, 0xf);  // row_half_mirror (^7)
        ARGMAX_DPP(vb, ib, 0x140, 0xf);  // row_mirror (^15)
        ARGMAX_DPP(vb, ib, 0x142, 0xa);  // row_bcast15 -> rows 1,3
        ARGMAX_DPP(vb, ib, 0x143, 0xc);  // row_bcast31 -> rows 2,3
        float wv = __int_as_float(__builtin_amdgcn_readlane(vb, 63));
        int wi = __builtin_amdgcn_readlane(ib, 63);
        if (lane == 0) sred[i & 1][w] = make_float2(wv, __int_as_float(wi));
        __syncthreads();
        // block reduce: lanes read sred[lane&15] (16-groups identical),
        // 4 within-row DPP steps -> every lane holds the block winner
        float2 c2 = sred[i & 1][lane & 15];
        int vb2 = __float_as_int(c2.x);
        int ib2 = __float_as_int(c2.y);
        ARGMAX_DPP(vb2, ib2, 0xB1, 0xf);
        ARGMAX_DPP(vb2, ib2, 0x4E, 0xf);
        ARGMAX_DPP(vb2, ib2, 0x141, 0xf);
        ARGMAX_DPP(vb2, ib2, 0x140, 0xf);
        int ii = __builtin_amdgcn_readfirstlane(ib2);  // uniform winner index
        const float* cp = base + (size_t)ii * 3;
        cx = cp[0]; cy = cp[1]; cz = cp[2];
        if (tid == 0) {
            float* o = out + ((size_t)b * NS + i) * 3;
            o[0] = cx; o[1] = cy; o[2] = cz;
        }
    }
}

// ------------- Ball query (exact expanded-form distance) + gather -------------
__global__ __launch_bounds__(256) void ballq_kernel(const float* __restrict__ xyz,
                                                    const float* __restrict__ pts,
                                                    const float* __restrict__ newxyz,
                                                    float* __restrict__ feat) {
    int w = threadIdx.x >> 6;
    int lane = threadIdx.x & 63;
    int wid = blockIdx.x * 4 + w;   // 0..4095 == b*512+s
    int b = wid >> 9;
    const float* nx = newxyz + (size_t)wid * 3;
    float cx = nx[0], cy = nx[1], cz = nx[2];
    float sa = __fadd_rn(__fadd_rn(__fmul_rn(cx, cx), __fmul_rn(cy, cy)),
                         __fmul_rn(cz, cz));
    __shared__ int sidx[4][64];
    const float* base = xyz + (size_t)b * NPTS * 3;
    int cnt = 0;
    for (int off = 0; off < NPTS && cnt < NK; off += 64) {
        int p = off + lane;
        float bx = base[p * 3 + 0], by = base[p * 3 + 1], bz = base[p * 3 + 2];
        float sb = __fadd_rn(__fadd_rn(__fmul_rn(bx, bx), __fmul_rn(by, by)),
                             __fmul_rn(bz, bz));
        float dt = __fadd_rn(__fadd_rn(__fmul_rn(cx, bx), __fmul_rn(cy, by)),
                             __fmul_rn(cz, bz));
        float sq = __fsub_rn(__fadd_rn(sa, sb), __fmul_rn(2.0f, dt));
        bool inb = !(sq > RAD2);           // strict >, matches reference
        unsigned long long mask = __ballot(inb);
        int pos = cnt + (int)__popcll(mask & ((1ull << lane) - 1ull));
        if (inb && pos < NK) sidx[w][pos] = p;
        cnt += (int)__popcll(mask);
    }
    __syncthreads();
    int filled = cnt < NK ? cnt : NK;
    int sel = (lane < filled) ? lane : 0;
    int p = (filled > 0) ? sidx[w][sel] : 0;  // filled>0 always (self in radius)
    float gx = base[p * 3 + 0], gy = base[p * 3 + 1], gz = base[p * 3 + 2];
    const float* pb = pts + (size_t)b * NPTS * 3;
    float q0 = pb[p * 3 + 0], q1 = pb[p * 3 + 1], q2 = pb[p * 3 + 2];
    float* fr = feat + ((size_t)wid * NK + lane) * 6;
    fr[0] = __fsub_rn(gx, cx);
    fr[1] = __fsub_rn(gy, cy);
    fr[2] = __fsub_rn(gz, cz);
    fr[3] = q0; fr[4] = q1; fr[5] = q2;
}

// ---------------- Layer-0 stats: per-channel sum/sumsq of h0raw ----------------
__global__ __launch_bounds__(256) void stats0_kernel(const float* __restrict__ feat,
                                                     const float* __restrict__ W0,
                                                     const float* __restrict__ b0,
                                                     float* __restrict__ stats) {
    int lane = threadIdx.x & 63;
    int wid = blockIdx.x * 4 + (threadIdx.x >> 6);  // 0..1023
    float w0[6];
#pragma unroll
    for (int j = 0; j < 6; ++j) w0[j] = W0[lane * 6 + j];
    float bb = b0[lane];
    float ssum = 0.f, ssq = 0.f;
    int r0 = wid * 256;
    for (int r = r0; r < r0 + 256; ++r) {
        const float* f = feat + (size_t)r * 6;
        float h = bb;
#pragma unroll
        for (int j = 0; j < 6; ++j) h = fmaf(w0[j], f[j], h);
        ssum += h;
        ssq = fmaf(h, h, ssq);
    }
    atomicAdd(&stats[lane], ssum);
    atomicAdd(&stats[64 + lane], ssq);
}

__global__ void fin0_kernel(const float* __restrict__ g0, const float* __restrict__ be0,
                            float* __restrict__ stats) {
    int c = threadIdx.x;  // 64 threads
    const float inv = 1.0f / (float)MTOT;  // 2^-18, exact
    float mu = stats[c] * inv;
    float var = fmaxf(stats[64 + c] * inv - mu * mu, 0.f);
    float a = g0[c] * rsqrtf(var + 1e-5f);
    stats[384 + c] = a;
    stats[448 + c] = fmaf(-mu, a, be0[c]);
}

// ---------------- Layer-1 stats: recompute h0n -> h1raw, sum/sumsq ----------------
__global__ __launch_bounds__(256) void stats1_kernel(const float* __restrict__ feat,
                                                     const float* __restrict__ W0,
                                                     const float* __restrict__ b0,
                                                     const float* __restrict__ W1,
                                                     const float* __restrict__ b1,
                                                     float* __restrict__ stats) {
    int lane = threadIdx.x & 63;
    int w = threadIdx.x >> 6;
    int half = w & 1;
    int pairG = blockIdx.x * 2 + (w >> 1);  // 0..2047
    int ch = half * 64 + lane;
    float w0r[6];
#pragma unroll
    for (int j = 0; j < 6; ++j) w0r[j] = W0[lane * 6 + j];
    float b0v = b0[lane];
    float a0 = stats[384 + lane], c0 = stats[448 + lane];
    float w1r[64];
#pragma unroll
    for (int j = 0; j < 64; ++j) w1r[j] = W1[ch * 64 + j];
    float b1v = b1[ch];
    float ssum = 0.f, ssq = 0.f;
    int r0 = pairG * 128;
    for (int r = r0; r < r0 + 128; ++r) {
        const float* f = feat + (size_t)r * 6;
        float h = b0v;
#pragma unroll
        for (int j = 0; j < 6; ++j) h = fmaf(w0r[j], f[j], h);
        float h0n = fmaxf(fmaf(a0, h, c0), 0.f);
        int hbits = __float_as_int(h0n);
        float a0c = 0.f, a1c = 0.f, a2c = 0.f, a3c = 0.f;
#pragma unroll
        for (int j = 0; j < 64; j += 4) {
            a0c = fmaf(w1r[j + 0], __int_as_float(__builtin_amdgcn_readlane(hbits, j + 0)), a0c);
            a1c = fmaf(w1r[j + 1], __int_as_float(__builtin_amdgcn_readlane(hbits, j + 1)), a1c);
            a2c = fmaf(w1r[j + 2], __int_as_float(__builtin_amdgcn_readlane(hbits, j + 2)), a2c);
            a3c = fmaf(w1r[j + 3], __int_as_float(__builtin_amdgcn_readlane(hbits, j + 3)), a3c);
        }
        float acc = b1v + ((a0c + a1c) + (a2c + a3c));
        ssum += acc;
        ssq = fmaf(acc, acc, ssq);
    }
    atomicAdd(&stats[128 + ch], ssum);
    atomicAdd(&stats[256 + ch], ssq);
}

__global__ void fin1_kernel(const float* __restrict__ g1, const float* __restrict__ be1,
                            float* __restrict__ stats) {
    int c = threadIdx.x;  // 128 threads
    const float inv = 1.0f / (float)MTOT;
    float mu = stats[128 + c] * inv;
    float var = fmaxf(stats[256 + c] * inv - mu * mu, 0.f);
    float a = g1[c] * rsqrtf(var + 1e-5f);
    stats[512 + c] = a;
    stats[640 + c] = fmaf(-mu, a, be1[c]);
}

// ---------------- Final: recompute h1n, max over K, write output ----------------
__global__ __launch_bounds__(256) void final_kernel(const float* __restrict__ feat,
                                                    const float* __restrict__ W0,
                                                    const float* __restrict__ b0,
                                                    const float* __restrict__ W1,
                                                    const float* __restrict__ b1,
                                                    const float* __restrict__ stats,
                                                    float* __restrict__ out) {
    int lane = threadIdx.x & 63;
    int w = threadIdx.x >> 6;
    int half = w & 1;
    int g = blockIdx.x * 2 + (w >> 1);  // 0..4095 == b*512+s
    int ch = half * 64 + lane;
    float w0r[6];
#pragma unroll
    for (int j = 0; j < 6; ++j) w0r[j] = W0[lane * 6 + j];
    float b0v = b0[lane];
    float a0 = stats[384 + lane], c0 = stats[448 + lane];
    float w1r[64];
#pragma unroll
    for (int j = 0; j < 64; ++j) w1r[j] = W1[ch * 64 + j];
    float b1v = b1[ch];
    float a1 = stats[512 + ch], c1 = stats[640 + ch];
    float mx = -1e30f;
    int r0 = g * 64;
    for (int k = 0; k < 64; ++k) {
        const float* f = feat + (size_t)(r0 + k) * 6;
        float h = b0v;
#pragma unroll
        for (int j = 0; j < 6; ++j) h = fmaf(w0r[j], f[j], h);
        float h0n = fmaxf(fmaf(a0, h, c0), 0.f);
        int hbits = __float_as_int(h0n);
        float a0c = 0.f, a1c = 0.f, a2c = 0.f, a3c = 0.f;
#pragma unroll
        for (int j = 0; j < 64; j += 4) {
            a0c = fmaf(w1r[j + 0], __int_as_float(__builtin_amdgcn_readlane(hbits, j + 0)), a0c);
            a1c = fmaf(w1r[j + 1], __int_as_float(__builtin_amdgcn_readlane(hbits, j + 1)), a1c);
            a2c = fmaf(w1r[j + 2], __int_as_float(__builtin_amdgcn_readlane(hbits, j + 2)), a2c);
            a3c = fmaf(w1r[j + 3], __int_as_float(__builtin_amdgcn_readlane(hbits, j + 3)), a3c);
        }
        float acc = b1v + ((a0c + a1c) + (a2c + a3c));
        float h1n = fmaxf(fmaf(a1, acc, c1), 0.f);
        mx = fmaxf(mx, h1n);
    }
    out[12288 + (size_t)g * 128 + ch] = mx;
}

extern "C" void kernel_launch(void* const* d_in, const int* in_sizes, int n_in,
                              void* d_out, int out_size, void* d_ws, size_t ws_size,
                              hipStream_t stream) {
    const float* xyz = (const float*)d_in[0];
    const float* pts = (const float*)d_in[1];
    const float* W0  = (const float*)d_in[2];
    const float* b0  = (const float*)d_in[3];
    const float* g0  = (const float*)d_in[4];
    const float* be0 = (const float*)d_in[5];
    const float* W1  = (const float*)d_in[6];
    const float* b1  = (const float*)d_in[7];
    const float* g1  = (const float*)d_in[8];
    const float* be1 = (const float*)d_in[9];
    float* out = (float*)d_out;

    float* feat  = (float*)d_ws;                     // 262144*6 floats = 6.29 MB
    float* stats = feat + (size_t)MTOT * 6;          // 768 floats

    // opt-in to 128 KB dynamic LDS for fps (idempotent, host-side, capture-safe)
    const int fps_lds = 2 * NPTS * (int)sizeof(float);  // 131072
    hipFuncSetAttribute(reinterpret_cast<const void*>(fps_kernel),
                        hipFuncAttributeMaxDynamicSharedMemorySize, fps_lds);

    hipMemsetAsync(stats, 0, 384 * sizeof(float), stream);
    fps_kernel<<<NB, 1024, fps_lds, stream>>>(xyz, out);
    ballq_kernel<<<1024, 256, 0, stream>>>(xyz, pts, out, feat);
    stats0_kernel<<<256, 256, 0, stream>>>(feat, W0, b0, stats);
    fin0_kernel<<<1, 64, 0, stream>>>(g0, be0, stats);
    stats1_kernel<<<1024, 256, 0, stream>>>(feat, W0, b0, W1, b1, stats);
    fin1_kernel<<<1, 128, 0, stream>>>(g1, be1, stats);
    final_kernel<<<2048, 256, 0, stream>>>(feat, W0, b0, W1, b1, stats, out);
}